// Round 1
// baseline (201.659 us; speedup 1.0000x reference)
//
#include <hip/hip_runtime.h>
#include <cstdint>

typedef short bf16x8 __attribute__((ext_vector_type(8)));
typedef float f32x4  __attribute__((ext_vector_type(4)));

#define TOK    64         // tokens per block
#define PITCH  264        // ushorts/row (256 + 8 pad; 132 dw = 4 mod 32 -> b128 tiles banks)
#define HROWS  (64 * PITCH)   // one K-half chunk buffer (64 code rows)
#define MAXC   24

__device__ __forceinline__ unsigned short f2bf(float f) {
  unsigned u = __float_as_uint(f);
  return (unsigned short)((u + 0x7FFFu + ((u >> 16) & 1u)) >> 16);
}
__device__ __forceinline__ uint4 pack8(float4 a, float4 b) {
  uint4 u;
  u.x = (unsigned)f2bf(a.x) | ((unsigned)f2bf(a.y) << 16);
  u.y = (unsigned)f2bf(a.z) | ((unsigned)f2bf(a.w) << 16);
  u.z = (unsigned)f2bf(b.x) | ((unsigned)f2bf(b.y) << 16);
  u.w = (unsigned)f2bf(b.z) | ((unsigned)f2bf(b.w) << 16);
  return u;
}

// ---------------------------------------------------------------------------
// Prep: cb_bf = bf16(cb), ee = ||cb_k||^2. Block 0 zeroes global accumulators.
// ---------------------------------------------------------------------------
__global__ __launch_bounds__(256) void vq_prep(const float* __restrict__ cb,
                                               unsigned short* __restrict__ cb_bf,
                                               float* __restrict__ ee,
                                               float* __restrict__ acc2,
                                               int* __restrict__ done_ctr, int K) {
  if (blockIdx.x == 0 && threadIdx.x == 0) {
    acc2[0] = 0.f; acc2[1] = 0.f; *done_ctr = 0;
  }
  int wave = threadIdx.x >> 6, lane = threadIdx.x & 63;
  int k = blockIdx.x * 4 + wave;
  if (k >= K) return;
  float4 v = *reinterpret_cast<const float4*>(cb + (size_t)k * 256 + lane * 4);
  float s = v.x * v.x + v.y * v.y + v.z * v.z + v.w * v.w;
  #pragma unroll
  for (int off = 32; off; off >>= 1) s += __shfl_down(s, off, 64);
  ushort4 b;
  b.x = f2bf(v.x); b.y = f2bf(v.y); b.z = f2bf(v.z); b.w = f2bf(v.w);
  *reinterpret_cast<ushort4*>(cb_bf + (size_t)k * 256 + lane * 4) = b;
  if (lane == 0) ee[k] = s;
}

// ---------------------------------------------------------------------------
// Main: 512 thr (8 waves = 2 K-halves x 4 token-sets), TOK=64, grid 512
// -> 2 blocks/CU (LDS ~78.6 KB) = 16 waves/CU = 4 waves/SIMD (was 2).
// Wave (kh = wv>>2, ts = wv&3): tokens [16ts,16ts+16) as 1 A-set in regs,
// K-half kh (512 codes = 8 chunks of 64). T14 pipeline: chunk lc+1's global
// loads (8x uint4/thread, coalesced) issued BEFORE chunk lc's MFMAs; the
// LDS write lands after the barrier, so L2 latency hides under compute.
// Screen gate = min(running amin, chunk min, global packed umin) -> candidate
// list of packed (fp32dist|idx) + atomicMin umin. Epilogue is two-tier: if
// exactly one candidate within error margin of umin -> zero rescore dots;
// else exact fp32 rescore of the in-margin set only.
// NO restrictive launch bound (R6's (512,4) spill catastrophe).
// ---------------------------------------------------------------------------
__global__ __launch_bounds__(512, 2) void vq_main(
    const float* __restrict__ z, const float* __restrict__ cb,
    const unsigned short* __restrict__ cb_bf, const float* __restrict__ ee,
    const float* __restrict__ mask,
    float* __restrict__ out_q, float* __restrict__ out_idx_f,
    float* __restrict__ out_loss, float* __restrict__ acc2,
    int* __restrict__ done_ctr, int nblocks, int K) {
  __shared__ __align__(16) unsigned short buf[128 * PITCH];  // 67584 B: z-stage, then 2 half-buffers
  __shared__ float ee_lds[1024];                             // 4 KB
  __shared__ float znorm[TOK];
  __shared__ int   ccnt[TOK];
  __shared__ unsigned umin[TOK];                             // packed (dist22|idx10) running min
  __shared__ unsigned cand[TOK * MAXC];                      // 6 KB packed candidates
  __shared__ float red[16];
  __shared__ bool  last;

  const int t = threadIdx.x;
  const int n0 = blockIdx.x * TOK;
  const int wv = t >> 6, lane = t & 63;
  const int kh = wv >> 2, ts = wv & 3;
  const int quad = lane >> 4, l15 = lane & 15;
  const int q16 = t & 15;

  // ---- code norms into LDS + eemax wave-reduce (piggybacks on z-stage sync) ----
  float ea = ee[t], eb = ee[t + 512];
  ee_lds[t] = ea; ee_lds[t + 512] = eb;
  if (t < TOK) { ccnt[t] = 0; umin[t] = 0x7F7FFC00u; }
  float em = fmaxf(ea, eb);
  #pragma unroll
  for (int off = 32; off; off >>= 1) em = fmaxf(em, __shfl_xor(em, off, 64));
  if (lane == 0) red[wv] = em;

  // ---- stage z -> bf16 into buf rows 0..63; ||z|| ----
  #pragma unroll
  for (int pass = 0; pass < 2; ++pass) {
    int row = pass * 32 + (t >> 4);
    const float* zr = z + (size_t)(n0 + row) * 256;
    float ssq = 0.f;
    #pragma unroll
    for (int j = 0; j < 2; ++j) {
      float4 a = *reinterpret_cast<const float4*>(zr + q16 * 16 + j * 8);
      float4 b = *reinterpret_cast<const float4*>(zr + q16 * 16 + j * 8 + 4);
      ssq += a.x*a.x + a.y*a.y + a.z*a.z + a.w*a.w
           + b.x*b.x + b.y*b.y + b.z*b.z + b.w*b.w;
      *reinterpret_cast<uint4*>(&buf[row * PITCH + q16 * 16 + j * 8]) = pack8(a, b);
    }
    #pragma unroll
    for (int off = 1; off < 16; off <<= 1) ssq += __shfl_xor(ssq, off, 64);
    if (q16 == 0) znorm[row] = sqrtf(ssq);
  }
  __syncthreads();  // S1: z staged, red[] written

  float enmax;
  {
    float m8 = red[0];
    #pragma unroll
    for (int i = 1; i < 8; ++i) m8 = fmaxf(m8, red[i]);
    enmax = sqrtf(m8);
  }

  // ---- prefetch chunk 0 into registers (global, no LDS hazard) ----
  const int tt = t & 255;                     // index within kh half-group
  const unsigned short* cbh = cb_bf + (size_t)kh * 512 * 256;
  uint4 st[8];
  #pragma unroll
  for (int u = 0; u < 8; ++u)
    st[u] = *reinterpret_cast<const uint4*>(cbh + (size_t)(u * 256 + tt) * 8);

  // ---- A fragments into registers ----
  bf16x8 afrag[8];
  float  znreg[4];
  {
    const unsigned short* za = &buf[(ts * 16 + l15) * PITCH + quad * 8];
    #pragma unroll
    for (int kk = 0; kk < 8; ++kk)
      afrag[kk] = *reinterpret_cast<const bf16x8*>(za + kk * 32);
    #pragma unroll
    for (int r = 0; r < 4; ++r)
      znreg[r] = znorm[ts * 16 + quad * 4 + r];
  }
  __syncthreads();  // S2: all A-loads done before chunk staging overwrites buf

  unsigned short* qbuf = &buf[kh * HROWS];
  #pragma unroll
  for (int u = 0; u < 8; ++u) {
    int f = u * 256 + tt;
    *reinterpret_cast<uint4*>(&qbuf[(f >> 5) * PITCH + (f & 31) * 8]) = st[u];
  }
  __syncthreads();  // S3: chunk 0 visible

  float amin[4] = {3.4e38f, 3.4e38f, 3.4e38f, 3.4e38f};

  // ---- chunk loop: 8 chunks x 64 codes per K-half ----
  for (int lc = 0; lc < 8; ++lc) {
    const int kbase = kh * 512 + lc * 64;
    if (lc < 7) {  // T14: issue next chunk's loads before compute
      const unsigned short* src = cbh + (size_t)(lc + 1) * 64 * 256;
      #pragma unroll
      for (int u = 0; u < 8; ++u)
        st[u] = *reinterpret_cast<const uint4*>(src + (size_t)(u * 256 + tt) * 8);
    }

    f32x4 acc[4];
    #pragma unroll
    for (int ct = 0; ct < 4; ++ct) acc[ct] = (f32x4){0.f, 0.f, 0.f, 0.f};
    __builtin_amdgcn_s_setprio(1);
    #pragma unroll
    for (int kk = 0; kk < 8; ++kk) {
      bf16x8 b0 = *reinterpret_cast<const bf16x8*>(&qbuf[(l15)      * PITCH + quad * 8 + kk * 32]);
      bf16x8 b1 = *reinterpret_cast<const bf16x8*>(&qbuf[(16 + l15) * PITCH + quad * 8 + kk * 32]);
      bf16x8 b2 = *reinterpret_cast<const bf16x8*>(&qbuf[(32 + l15) * PITCH + quad * 8 + kk * 32]);
      bf16x8 b3 = *reinterpret_cast<const bf16x8*>(&qbuf[(48 + l15) * PITCH + quad * 8 + kk * 32]);
      acc[0] = __builtin_amdgcn_mfma_f32_16x16x32_bf16(afrag[kk], b0, acc[0], 0, 0, 0);
      acc[1] = __builtin_amdgcn_mfma_f32_16x16x32_bf16(afrag[kk], b1, acc[1], 0, 0, 0);
      acc[2] = __builtin_amdgcn_mfma_f32_16x16x32_bf16(afrag[kk], b2, acc[2], 0, 0, 0);
      acc[3] = __builtin_amdgcn_mfma_f32_16x16x32_bf16(afrag[kk], b3, acc[3], 0, 0, 0);
    }
    __builtin_amdgcn_s_setprio(0);

    // screen: margin >= 2*eps(bf16) + 0.13 (umin/cand 22-bit dist truncation)
    float e0 = ee_lds[kbase + l15],      e1 = ee_lds[kbase + 16 + l15];
    float e2 = ee_lds[kbase + 32 + l15], e3 = ee_lds[kbase + 48 + l15];
    float en0 = sqrtf(e0), en1 = sqrtf(e1), en2 = sqrtf(e2), en3 = sqrtf(e3);
    #pragma unroll
    for (int r = 0; r < 4; ++r) {
      float d0 = e0 - 2.f * acc[0][r];
      float d1 = e1 - 2.f * acc[1][r];
      float d2 = e2 - 2.f * acc[2][r];
      float d3 = e3 - 2.f * acc[3][r];
      float w = fminf(fminf(d0, d1), fminf(d2, d3));
      #pragma unroll
      for (int off = 1; off < 16; off <<= 1) w = fminf(w, __shfl_xor(w, off, 64));
      int tok = ts * 16 + quad * 4 + r;
      float gq = __uint_as_float(umin[tok] & 0xFFFFFC00u);  // stale-read ok (conservative)
      float am = fminf(fminf(amin[r], w), gq);
      amin[r] = am;
      float zn = znreg[r];
      if (d0 <= am + 1.63f + 0.002f * zn * en0) {
        unsigned pu = (__float_as_uint(fmaxf(d0, 0.f)) & 0xFFFFFC00u) | (unsigned)(kbase + l15);
        atomicMin(&umin[tok], pu);
        int sl = atomicAdd(&ccnt[tok], 1);
        if (sl < MAXC) cand[tok * MAXC + sl] = pu;
      }
      if (d1 <= am + 1.63f + 0.002f * zn * en1) {
        unsigned pu = (__float_as_uint(fmaxf(d1, 0.f)) & 0xFFFFFC00u) | (unsigned)(kbase + 16 + l15);
        atomicMin(&umin[tok], pu);
        int sl = atomicAdd(&ccnt[tok], 1);
        if (sl < MAXC) cand[tok * MAXC + sl] = pu;
      }
      if (d2 <= am + 1.63f + 0.002f * zn * en2) {
        unsigned pu = (__float_as_uint(fmaxf(d2, 0.f)) & 0xFFFFFC00u) | (unsigned)(kbase + 32 + l15);
        atomicMin(&umin[tok], pu);
        int sl = atomicAdd(&ccnt[tok], 1);
        if (sl < MAXC) cand[tok * MAXC + sl] = pu;
      }
      if (d3 <= am + 1.63f + 0.002f * zn * en3) {
        unsigned pu = (__float_as_uint(fmaxf(d3, 0.f)) & 0xFFFFFC00u) | (unsigned)(kbase + 48 + l15);
        atomicMin(&umin[tok], pu);
        int sl = atomicAdd(&ccnt[tok], 1);
        if (sl < MAXC) cand[tok * MAXC + sl] = pu;
      }
    }
    __syncthreads();  // all reads of qbuf done across block
    if (lc < 7) {
      #pragma unroll
      for (int u = 0; u < 8; ++u) {
        int f = u * 256 + tt;
        *reinterpret_cast<uint4*>(&qbuf[(f >> 5) * PITCH + (f & 31) * 8]) = st[u];
      }
      __syncthreads();  // next chunk visible
    }
  }

  // ---- two-tier epilogue: 8 waves x 8 tokens ----
  float lsum = 0.f, msum = 0.f;
  for (int it = 0; it < 8; ++it) {
    int tok = wv * 8 + it;
    int n = n0 + tok;
    float4 zv = *reinterpret_cast<const float4*>(z + (size_t)n * 256 + lane * 4);
    int cnt = ccnt[tok];
    int bk = 0;
    if (cnt > MAXC) {  // overflow safety net: exact scan of all K
      float bs = 3.4e38f;
      for (int k = 0; k < K; ++k) {
        float4 ev = *reinterpret_cast<const float4*>(cb + (size_t)k * 256 + lane * 4);
        float dp = zv.x * ev.x + zv.y * ev.y + zv.z * ev.z + zv.w * ev.w;
        #pragma unroll
        for (int off = 32; off; off >>= 1) dp += __shfl_xor(dp, off, 64);
        float s = ee_lds[k] - 2.f * dp;
        if (s < bs) { bs = s; bk = k; }
      }
    } else {
      unsigned pm = umin[tok];
      float thr = __uint_as_float(pm & 0xFFFFFC00u)
                + 1.63f + 0.002f * znorm[tok] * enmax;
      int c = (lane < cnt) ? lane : 0;
      unsigned pe = cand[tok * MAXC + c];
      bool flag = (lane < cnt) && (__uint_as_float(pe & 0xFFFFFC00u) <= thr);
      unsigned long long msk = __ballot(flag);
      if (__popcll(msk) == 1) {
        bk = (int)(pm & 1023u);   // unique in-margin candidate == exact argmin
      } else {
        float bs = 3.4e38f; bk = 1 << 29;
        while (msk) {
          int cc = __ffsll(msk) - 1;
          msk &= msk - 1;
          unsigned pc = cand[tok * MAXC + cc];
          int k = (int)(pc & 1023u);
          float4 ev = *reinterpret_cast<const float4*>(cb + (size_t)k * 256 + lane * 4);
          float dp = zv.x * ev.x + zv.y * ev.y + zv.z * ev.z + zv.w * ev.w;
          #pragma unroll
          for (int off = 32; off; off >>= 1) dp += __shfl_xor(dp, off, 64);
          float s = ee_lds[k] - 2.f * dp;   // identical on all lanes
          if (s < bs || (s == bs && k < bk)) { bs = s; bk = k; }
        }
      }
    }
    float m = mask[n];
    float4 qv = *reinterpret_cast<const float4*>(cb + (size_t)bk * 256 + lane * 4);
    float4 o; o.x = qv.x * m; o.y = qv.y * m; o.z = qv.z * m; o.w = qv.w * m;
    *reinterpret_cast<float4*>(out_q + (size_t)n * 256 + lane * 4) = o;
    float dx = zv.x - qv.x, dy = zv.y - qv.y, dz = zv.z - qv.z, dw = zv.w - qv.w;
    lsum = fmaf(m, dx * dx + dy * dy + dz * dz + dw * dw, lsum);
    if (lane == 0) {
      msum += m;
      out_idx_f[n] = (m > 0.f) ? (float)bk : 0.f;
    }
  }
  #pragma unroll
  for (int off = 32; off; off >>= 1) lsum += __shfl_down(lsum, off, 64);
  if (lane == 0) { red[wv] = lsum; red[8 + wv] = msum; }
  __syncthreads();
  if (t == 0) {
    float a = 0.f, b = 0.f;
    #pragma unroll
    for (int i = 0; i < 8; ++i) { a += red[i]; b += red[8 + i]; }
    atomicAdd(&acc2[0], a);
    atomicAdd(&acc2[1], b);
    __threadfence();
    int prev = atomicAdd(done_ctr, 1);
    last = (prev == nblocks - 1);
  }
  __syncthreads();
  if (last && t == 0) {
    float s  = atomicAdd(&acc2[0], 0.0f);
    float nv = atomicAdd(&acc2[1], 0.0f);
    out_loss[0] = (nv > 0.f) ? (0.25f * s / (nv * 256.0f)) : 0.0f;
  }
}

// ---------------------------------------------------------------------------
extern "C" void kernel_launch(void* const* d_in, const int* in_sizes, int n_in,
                              void* d_out, int out_size, void* d_ws, size_t ws_size,
                              hipStream_t stream) {
  const float* z    = (const float*)d_in[0];  // (N, 256)
  const float* mask = (const float*)d_in[1];  // (N,)
  const float* cb   = (const float*)d_in[2];  // (K, 256)
  const int N = in_sizes[1];                  // 32768
  const int D = 256;
  const int K = in_sizes[2] / D;              // 1024

  float* wsf  = (float*)d_ws;
  float* acc2 = wsf;                          // 2 floats
  int*   dctr = (int*)(wsf + 2);              // 1 int
  float* ee   = wsf + 8;                      // K floats
  unsigned short* cb_bf = (unsigned short*)(ee + K);  // K*256 bf16

  float* out_q     = (float*)d_out;           // N*D
  float* out_loss  = out_q + (size_t)N * D;   // 1
  float* out_idx_f = out_loss + 1;            // N

  vq_prep<<<(K + 3) / 4, 256, 0, stream>>>(cb, cb_bf, ee, acc2, dctr, K);
  vq_main<<<N / TOK, 512, 0, stream>>>(z, cb, cb_bf, ee, mask, out_q,
                                       out_idx_f, out_loss, acc2, dctr, N / TOK, K);
}